// Round 4
// baseline (4851.147 us; speedup 1.0000x reference)
//
#include <hip/hip_runtime.h>
#include <stdint.h>

#define BATCH 512
#define SEQ   512
#define HID   128
#define BT    16        // batch tile per chain
#define ROWB  528       // LDS act row stride in bytes
#define NPAIR 16        // pairs of batch tiles (2 chains per block)
#define CH    8         // steps per sync chunk
#define RING  64        // ring slots (steps) per layer boundary
#define FPAD  32        // ints per flag (128B, kills false sharing)

typedef _Float16 half8 __attribute__((ext_vector_type(8)));
typedef float f32x4 __attribute__((ext_vector_type(4)));
typedef unsigned long long u64;

union UHP { uint32_t u; _Float16 h[2]; };
__device__ __forceinline__ uint32_t pack2f(float a, float b){
  UHP r; r.h[0] = (_Float16)a; r.h[1] = (_Float16)b; return r.u;
}

__device__ __forceinline__ float rcp_(float x){
#if __has_builtin(__builtin_amdgcn_rcpf)
  return __builtin_amdgcn_rcpf(x);
#else
  return 1.f / x;
#endif
}
__device__ __forceinline__ float exp2_(float x){
#if __has_builtin(__builtin_amdgcn_exp2f)
  return __builtin_amdgcn_exp2f(x);
#else
  return exp2f(x);
#endif
}
__device__ __forceinline__ float sigm(float x){ return rcp_(1.f + exp2_(x * -1.44269504f)); }
__device__ __forceinline__ float tanh_(float x){ return 1.f - 2.f * rcp_(exp2_(x * 2.88539008f) + 1.f); }

// MODE 0: x fp32 -> ring0 ; MODE 1: ring0 -> ring1 ; MODE 2: ring1 -> y fp32
template<int MODE>
__device__ __forceinline__ void run_layer(
    const float* __restrict__ Wih, const float* __restrict__ Whh,
    const float* __restrict__ bih, const float* __restrict__ bhh,
    const float* __restrict__ x, uint32_t* __restrict__ rin,
    uint32_t* __restrict__ rout, float* __restrict__ y,
    int* src_ready, int* src_done, int* dst_ready, int* dst_done,
    int b0, int ctid, bool leader, char* act0, char* act1)
{
  const int lane = ctid & 63;
  const int w    = ctid >> 6;
  const int u0   = w * 16;
  const int rm   = lane & 15;   // batch col within tile
  const int kq   = lane >> 4;   // k-quarter / acc row group

  // ---- weights -> f16 register fragments (A: 16 units x 32 k per frag)
  half8 wf[4][8];
  #pragma unroll
  for (int g = 0; g < 4; ++g){
    const int grow = g * HID + u0 + rm;
    #pragma unroll
    for (int s = 0; s < 8; ++s){
      const int k = s * 32 + kq * 8;
      const float* src = (s < 4) ? (Wih + (size_t)grow * HID + k)
                                 : (Whh + (size_t)grow * HID + (k - HID));
      const float4 aa = *(const float4*)src;
      const float4 bb = *(const float4*)(src + 4);
      half8 hh;
      hh[0]=(_Float16)aa.x; hh[1]=(_Float16)aa.y; hh[2]=(_Float16)aa.z; hh[3]=(_Float16)aa.w;
      hh[4]=(_Float16)bb.x; hh[5]=(_Float16)bb.y; hh[6]=(_Float16)bb.z; hh[7]=(_Float16)bb.w;
      wf[g][s] = hh;
    }
  }
  f32x4 bias4[4];
  #pragma unroll
  for (int g = 0; g < 4; ++g)
    #pragma unroll
    for (int r = 0; r < 4; ++r){
      const int row = g * HID + u0 + kq * 4 + r;
      bias4[g][r] = bih[row] + bhh[row];
    }

  // ---- staging thread mapping: 16 rows x 128 f16
  const int sb = ctid >> 5;   // 0..15 batch row
  const int sk = ctid & 31;   // col group
  float4 pf0; u64 pf1;

  auto issue_load = [&](int t){
    if constexpr (MODE == 0){
      pf0 = *(const float4*)(x + ((size_t)(b0 + sb) * SEQ + t) * HID + sk * 4);
    } else {
      u64* p = (u64*)(rin + ((size_t)(t & (RING-1)) * BATCH + b0 + sb) * 64 + sk * 2);
      pf1 = __hip_atomic_load(p, __ATOMIC_RELAXED, __HIP_MEMORY_SCOPE_AGENT);
    }
  };
  auto write_in = [&](char* buf){
    if constexpr (MODE == 0){
      uint2 v; v.x = pack2f(pf0.x, pf0.y); v.y = pack2f(pf0.z, pf0.w);
      *(uint2*)(buf + sb * ROWB + sk * 8) = v;
    } else {
      *(u64*)(buf + sb * ROWB + sk * 8) = pf1;
    }
  };
  auto wait_src = [&](int chunks){       // consumer: wait for producer progress
    if constexpr (MODE != 0){
      while (__hip_atomic_load(src_ready, __ATOMIC_RELAXED, __HIP_MEMORY_SCOPE_AGENT) < chunks)
        __builtin_amdgcn_s_sleep(2);
    }
  };
  auto wait_dst = [&](int chunks){       // producer: ring back-pressure
    if constexpr (MODE != 2){
      while (__hip_atomic_load(dst_done, __ATOMIC_RELAXED, __HIP_MEMORY_SCOPE_AGENT) < chunks)
        __builtin_amdgcn_s_sleep(2);
    }
  };

  // ---- prologue: stage input(0) into buf0, zero h region of buf0
  wait_src(1);
  issue_load(0);
  write_in(act0);
  if (ctid < 256)
    *(uint4*)(act0 + (ctid >> 4) * ROWB + 256 + (ctid & 15) * 16) = make_uint4(0u,0u,0u,0u);
  __syncthreads();

  f32x4 c4 = {0.f, 0.f, 0.f, 0.f};
  const int boff = rm * ROWB + kq * 16;
  int cur = 0;

  uint2 hp = {0u, 0u};     // deferred-store state (h of step t-1)
  float hv0=0.f, hv1=0.f, hv2=0.f, hv3=0.f;

  for (int t = 0; t < SEQ; ++t){
    char* bc = cur ? act1 : act0;
    char* bn = cur ? act0 : act1;
    const int tn = t + 1;

    // ---- flush deferred global store for step t-1 (post-barrier: a full
    // compute phase before the next vmcnt(0) drain)
    if (t > 0){
      if constexpr (MODE != 2){
        const u64 hp64 = ((u64)hp.y << 32) | (u64)hp.x;
        u64* p = (u64*)(rout + ((size_t)((t-1) & (RING-1)) * BATCH + b0 + rm) * 64 + (u0 >> 1) + kq * 2);
        __hip_atomic_store(p, hp64, __ATOMIC_RELAXED, __HIP_MEMORY_SCOPE_AGENT);
      } else {
        const size_t yb = ((size_t)(t-1) * HID + u0 + kq * 4) * BATCH + b0 + rm;
        y[yb]             = hv0;
        y[yb + BATCH]     = hv1;
        y[yb + 2 * BATCH] = hv2;
        y[yb + 3 * BATCH] = hv3;
      }
    }
    // ---- flag publishes (leader thread of the pair; stores for chunk k are
    // fully drained by the barrier at end of step 8k+8 -> publish at t=8k+9)
    if (leader){
      if constexpr (MODE != 2){
        if ((t & (CH-1)) == 1 && t >= 9)
          __hip_atomic_store(dst_ready, (t-1) >> 3, __ATOMIC_RELAXED, __HIP_MEMORY_SCOPE_AGENT);
      }
      if constexpr (MODE != 0){
        if ((t & (CH-1)) == 0 && t > 0)
          __hip_atomic_store(src_done, t >> 3, __ATOMIC_RELAXED, __HIP_MEMORY_SCOPE_AGENT);
      }
    }

    if (tn < SEQ && (tn & (CH-1)) == 0) wait_src((tn >> 3) + 1);
    if ((t & (CH-1)) == 0 && t >= RING) wait_dst((t >> 3) - 7);
    if (tn < SEQ) issue_load(tn);       // global prefetch overlaps compute

    f32x4 a0 = bias4[0], a1 = bias4[1], a2 = bias4[2], a3 = bias4[3];
    #pragma unroll
    for (int s = 0; s < 8; ++s){
      const half8 bf = *(const half8*)(bc + boff + s * 64);
      a0 = __builtin_amdgcn_mfma_f32_16x16x32_f16(wf[0][s], bf, a0, 0, 0, 0);
      a1 = __builtin_amdgcn_mfma_f32_16x16x32_f16(wf[1][s], bf, a1, 0, 0, 0);
      a2 = __builtin_amdgcn_mfma_f32_16x16x32_f16(wf[2][s], bf, a2, 0, 0, 0);
      a3 = __builtin_amdgcn_mfma_f32_16x16x32_f16(wf[3][s], bf, a3, 0, 0, 0);
    }

    // elementwise fully in-register: lane holds i,f,g,o for 4 units, 1 batch col
    float hvr[4];
    #pragma unroll
    for (int r = 0; r < 4; ++r){
      const float ii = sigm(a0[r]), ff = sigm(a1[r]);
      const float gg = tanh_(a2[r]), oo = sigm(a3[r]);
      c4[r] = ff * c4[r] + ii * gg;
      hvr[r] = oo * tanh_(c4[r]);
    }
    hp.x = pack2f(hvr[0], hvr[1]);
    hp.y = pack2f(hvr[2], hvr[3]);
    hv0 = hvr[0]; hv1 = hvr[1]; hv2 = hvr[2]; hv3 = hvr[3];

    // next-step operands -> other buffer; single barrier per step
    *(uint2*)(bn + rm * ROWB + 256 + u0 * 2 + kq * 8) = hp;
    if (tn < SEQ) write_in(bn);
    __syncthreads();
    cur ^= 1;
  }

  // ---- tail: flush step SEQ-1, drain, final publish
  if constexpr (MODE != 2){
    const u64 hp64 = ((u64)hp.y << 32) | (u64)hp.x;
    u64* p = (u64*)(rout + ((size_t)((SEQ-1) & (RING-1)) * BATCH + b0 + rm) * 64 + (u0 >> 1) + kq * 2);
    __hip_atomic_store(p, hp64, __ATOMIC_RELAXED, __HIP_MEMORY_SCOPE_AGENT);
  } else {
    const size_t yb = ((size_t)(SEQ-1) * HID + u0 + kq * 4) * BATCH + b0 + rm;
    y[yb]             = hv0;
    y[yb + BATCH]     = hv1;
    y[yb + 2 * BATCH] = hv2;
    y[yb + 3 * BATCH] = hv3;
  }
  __syncthreads();   // drains vmcnt: all stores of both chains complete
  if (leader){
    if constexpr (MODE != 2)
      __hip_atomic_store(dst_ready, SEQ / CH, __ATOMIC_RELAXED, __HIP_MEMORY_SCOPE_AGENT);
    if constexpr (MODE != 0)
      __hip_atomic_store(src_done, SEQ / CH, __ATOMIC_RELAXED, __HIP_MEMORY_SCOPE_AGENT);
  }
}

// Grid: 48 blocks (3 layers x 16 pairs) x 1024 threads (16 waves, 2 chains).
// Chains A/B of a block are two adjacent batch tiles, barrier-locked; their
// producers live in one upstream block, so rates match by construction.
__global__ __launch_bounds__(1024, 4) void lstm_pipe(
    const float* W0i, const float* W0h, const float* b0i, const float* b0h,
    const float* W1i, const float* W1h, const float* b1i, const float* b1h,
    const float* W2i, const float* W2h, const float* b2i, const float* b2h,
    const float* x, float* y, uint32_t* ring, int* flags)
{
  const int layer = blockIdx.x / NPAIR;        // 0,1,2
  const int pair  = blockIdx.x % NPAIR;
  const int chain = threadIdx.x >> 9;          // 0,1
  const int ctid  = threadIdx.x & 511;
  const int tile  = pair * 2 + chain;
  const int b0    = tile * BT;
  const bool leader = (threadIdx.x == 0);

  __shared__ char act[2][2][BT * ROWB];        // [chain][buf]

  uint32_t* r0 = ring;                                 // boundary 0: L0 -> L1
  uint32_t* r1 = ring + (size_t)RING * BATCH * 64;     // boundary 1: L1 -> L2

  // flags per pair: [0]=b0_ready [1]=b0_done [2]=b1_ready [3]=b1_done
  int* f0r = flags + (0 * NPAIR + pair) * FPAD;
  int* f0d = flags + (1 * NPAIR + pair) * FPAD;
  int* f1r = flags + (2 * NPAIR + pair) * FPAD;
  int* f1d = flags + (3 * NPAIR + pair) * FPAD;

  char* a0 = act[chain][0];
  char* a1 = act[chain][1];

  if (layer == 0){
    run_layer<0>(W0i, W0h, b0i, b0h, x, nullptr, r0, nullptr,
                 nullptr, nullptr, f0r, f0d, b0, ctid, leader, a0, a1);
  } else if (layer == 1){
    run_layer<1>(W1i, W1h, b1i, b1h, nullptr, r0, r1, nullptr,
                 f0r, f0d, f1r, f1d, b0, ctid, leader, a0, a1);
  } else {
    run_layer<2>(W2i, W2h, b2i, b2h, nullptr, r1, nullptr, y,
                 f1r, f1d, nullptr, nullptr, b0, ctid, leader, a0, a1);
  }
}

extern "C" void kernel_launch(void* const* d_in, const int* in_sizes, int n_in,
                              void* d_out, int out_size, void* d_ws, size_t ws_size,
                              hipStream_t stream) {
  const float* x    = (const float*)d_in[0];
  const float* Wih0 = (const float*)d_in[1];
  const float* Whh0 = (const float*)d_in[2];
  const float* bih0 = (const float*)d_in[3];
  const float* bhh0 = (const float*)d_in[4];
  const float* Wih1 = (const float*)d_in[5];
  const float* Whh1 = (const float*)d_in[6];
  const float* bih1 = (const float*)d_in[7];
  const float* bhh1 = (const float*)d_in[8];
  const float* Wih2 = (const float*)d_in[9];
  const float* Whh2 = (const float*)d_in[10];
  const float* bih2 = (const float*)d_in[11];
  const float* bhh2 = (const float*)d_in[12];

  float* out = (float*)d_out;
  uint32_t* ring = (uint32_t*)d_ws;
  const size_t ring_bytes = (size_t)2 * RING * BATCH * 64 * 4;   // 16 MiB
  int* flags = (int*)((char*)d_ws + ring_bytes);

  hipMemsetAsync(flags, 0, 4 * NPAIR * FPAD * sizeof(int), stream);

  dim3 grid(3 * NPAIR), block(1024);
  lstm_pipe<<<grid, block, 0, stream>>>(
      Wih0, Whh0, bih0, bhh0, Wih1, Whh1, bih1, bhh1, Wih2, Whh2, bih2, bhh2,
      x, out, ring, flags);
}